// Round 12
// baseline (427.521 us; speedup 1.0000x reference)
//
#include <hip/hip_runtime.h>
#include <math.h>

// Problem constants (from reference setup_inputs)
namespace {
constexpr int B = 128;
constexpr int T = 2048;
constexpr int D = 128;
constexpr int P = 64;
constexpr int TOUT = T + P;          // 2112
constexpr int NC = 32;               // chunks along T (best measured)
constexpr int L = T / NC;            // 64 per chunk
constexpr float ALPHA = 0.94f;
constexpr float OMA = (float)(1.0 - 0.94);   // 1-alpha
constexpr float OMA_HALF = 0.03f;            // 0.5*(1-alpha)
constexpr float UCLIP = 1e-6f;
constexpr float INV_SQRT2 = 0.70710678118654752f;
}

// ---------------------------------------------------------------------------
// Direct composite map z = ndtri(student_t4_cdf(t)) = t * h(t^2), with
// h(q) a degree-4 polynomial in rc = 1/(8+q). Valid for q in [0, 33.34]
// (provable: ewma >= (1-alpha)(x-mu)^2 ==> t^2 <= 2/(1-alpha)).
// Max z err ~6e-3 vs 0.765 threshold; reference's u-clip never triggers.
// (Verified passing R9/R10, absmax 0.015625.)
// ---------------------------------------------------------------------------
__device__ __forceinline__ float t_to_z_direct(float y, float vv) {
    float it = __builtin_amdgcn_rsqf(vv);     // 1/scale
    float t  = y * it;                        // student-t variate
    float q  = t * t;                         // in [0, 33.34]
    float rc = __builtin_amdgcn_rcpf(8.0f + q);
    float p;
    p = fmaf(-1453.744128f, rc, 610.201088f); // b4, b3  (8^k-scaled)
    p = fmaf(p, rc, -98.038976f);             // b2
    p = fmaf(p, rc, 10.835976f);              // b1
    p = fmaf(p, rc, 0.280213f);               // b0
    return t * p;
}

// ---------------------------------------------------------------------------
// Kernel A': per (b, chunk) — chunk-local partials (old kA), then the LAST
// block to finish for batch b (device-scope atomic counter) performs the
// stitch for that batch (old kB), writing the folded half-carry crw into
// Spart (aliased) plus loc/scf. No co-residency assumption: non-last blocks
// simply exit; release via per-thread __threadfence() before the atomic,
// acquire via __threadfence() after winning.
// Aliasing (same as old kB): carry1 -> Spart, carry2 -> l1e, final crw ->
// Spart; every read at index o precedes the write at o in the same thread.
// NO __restrict__ on those three.
// ---------------------------------------------------------------------------
__global__ __launch_bounds__(128) void kA(const float* __restrict__ x,
                                          float* Spart,
                                          float* l1e,
                                          float* l2e,
                                          float* __restrict__ loc,
                                          float* __restrict__ scf,
                                          unsigned int* __restrict__ cnt) {
    const int c = blockIdx.x;      // chunk
    const int b = blockIdx.y;      // batch
    const int d = threadIdx.x;     // feature

    // ---- chunk-local partials (identical to R9 kA) ----
    {
        const float* xp = x + ((size_t)b * T + (size_t)c * L) * D + d;
        float x0 = xp[0];
        float sum = x0, l1, l2;
        if (c == 0) { l1 = x0;       l2 = x0 * x0; }
        else        { l1 = OMA * x0; l2 = OMA * (x0 * x0); }
        for (int k = 1; k < L; ++k) {
            float xv = xp[(size_t)k * D];
            sum += xv;
            l1 = fmaf(ALPHA, l1, OMA * xv);
            l2 = fmaf(ALPHA, l2, OMA * (xv * xv));
        }
        const size_t o = ((size_t)b * NC + c) * D + d;
        Spart[o] = sum; l1e[o] = l1; l2e[o] = l2;
    }

    // ---- last-block-done election ----
    __shared__ int isLast;
    __threadfence();                 // release this thread's partial stores
    __syncthreads();                 // all threads of block fenced
    if (threadIdx.x == 0) {
        unsigned int old = atomicAdd(&cnt[b], 1u);
        isLast = (old == NC - 1);
    }
    __syncthreads();
    if (!isLast) return;
    __threadfence();                 // acquire: predecessors' stores visible

    // ---- stitch for batch b (identical arithmetic to R9 kB) ----
    {
        const float alphaL = (float)pow((double)ALPHA, (double)L);  // folded
        float sum = 0.0f, e1 = 0.0f, e2 = 0.0f;
        for (int j = 0; j < NC; ++j) {
            const size_t o = ((size_t)b * NC + j) * D + d;
            float sp = Spart[o];
            float t1 = l1e[o];
            float t2 = l2e[o];
            Spart[o] = e1;           // carry1 (raw E1_end[j-1])
            l1e[o]   = e2;           // carry2 (raw E2_end[j-1])
            sum += sp;
            e1 = t1 + alphaL * e1;
            e2 = t2 + alphaL * e2;
        }
        const float mu = sum * (1.0f / (float)T);
        loc[b * D + d] = mu;
        float ew = fmaxf(fmaf(mu, mu, fmaf(-2.0f * mu, e1, e2)), 0.0f);
        scf[b * D + d] = fmaxf(sqrtf(0.5f * ew), 1e-5f);

        // fold: crw_half = 0.5*c2 - mu*c1 -> Spart
        for (int j = 0; j < NC; ++j) {
            const size_t o = ((size_t)b * NC + j) * D + d;
            float c1 = Spart[o];
            float c2 = l1e[o];
            Spart[o] = fmaf(-mu, c1, 0.5f * c2);
        }
    }
}

// ---------------------------------------------------------------------------
// Kernel C': per (b, chunk) — single fused EWMA scan of the 0.5-scaled
// variable (R9 structure, identical math), NT stores; the c == NC-1 blocks
// append the P=64 forecast rows (old kD; numerics validated in R10).
// ---------------------------------------------------------------------------
__global__ __launch_bounds__(128) void kC(const float* __restrict__ x,
                                          const float* __restrict__ crwb,
                                          const float* __restrict__ locg,
                                          const float* __restrict__ scfg,
                                          const float* __restrict__ zf,
                                          float* __restrict__ out) {
    const int c = blockIdx.x;
    const int b = blockIdx.y;
    const int d = threadIdx.x;

    const size_t co = ((size_t)b * NC + c) * D + d;
    const float crw   = crwb[co];              // 0.5-scaled folded carry
    const float mu    = locg[b * D + d];
    const float twomu = 2.0f * mu;
    const float mu2h  = 0.5f * mu * mu;

    const float* xp = x   + ((size_t)b * T    + (size_t)c * L) * D + d;
    float*       op = out + ((size_t)b * TOUT + (size_t)c * L) * D + d;

    float xv = xp[0];
    float g  = xv * (xv - twomu);
    float base = (c == 0) ? 0.5f * g : OMA_HALF * g;
    float s  = fmaf(ALPHA, crw, base);
    float vv = fmaxf(s + mu2h, 1e-10f);
    __builtin_nontemporal_store(t_to_z_direct(xv - mu, vv), &op[0]);

    for (int k = 1; k < L; ++k) {
        xv = xp[(size_t)k * D];
        g  = xv * (xv - twomu);
        s  = fmaf(ALPHA, s, OMA_HALF * g);
        vv = fmaxf(s + mu2h, 1e-10f);
        __builtin_nontemporal_store(t_to_z_direct(xv - mu, vv), &op[(size_t)k * D]);
    }

    // ---- forecasts (old kD) on the c == NC-1 blocks ----
    if (c == NC - 1) {
        const float sc = scfg[b * D + d];
        const float* zp = zf  + (size_t)b * P * D + d;
        float*       fp = out + ((size_t)b * TOUT + T) * D + d;

        for (int p = 0; p < P; ++p) {
            float zv = zp[(size_t)p * D];
            float u = 0.5f * erfcf(-zv * INV_SQRT2);            // ndtr
            u = fminf(fmaxf(u, UCLIP), 1.0f - UCLIP);

            float a = 4.0f * u * (1.0f - u);
            a = fminf(fmaxf(a, UCLIP), 1.0f);
            float sa = sqrtf(a);
            float inner = cosf(acosf(sa) * (1.0f / 3.0f)) / sa - 1.0f;
            float qv = 2.0f * sqrtf(fmaxf(inner, 0.0f));

            float sgn = (u > 0.5f) ? 1.0f : ((u < 0.5f) ? -1.0f : 0.0f);
            float val = fmaf(sgn * qv, sc, mu);

            __builtin_nontemporal_store(val, &fp[(size_t)p * D]);
        }
    }
}

// ---------------------------------------------------------------------------
extern "C" void kernel_launch(void* const* d_in, const int* in_sizes, int n_in,
                              void* d_out, int out_size, void* d_ws, size_t ws_size,
                              hipStream_t stream) {
    const float* x  = (const float*)d_in[0];   // (B,T,D)
    const float* zf = (const float*)d_in[1];   // (B,P,D)
    float* out = (float*)d_out;                // (B,T+P,D)

    float* ws = (float*)d_ws;
    const size_t NCH = (size_t)B * NC * D;     // 524288
    float* Spart = ws;                         // partials -> carries -> crw
    float* l1e   = Spart + NCH;                // tails -> carry2 scratch
    float* l2e   = l1e + NCH;
    float* loc   = l2e + NCH;                  // B*D
    float* scf   = loc + (size_t)B * D;        // B*D
    unsigned int* cnt = (unsigned int*)(scf + (size_t)B * D);  // B counters

    hipMemsetAsync(cnt, 0, B * sizeof(unsigned int), stream);
    kA<<<dim3(NC, B), 128, 0, stream>>>(x, Spart, l1e, l2e, loc, scf, cnt);
    kC<<<dim3(NC, B), 128, 0, stream>>>(x, Spart, loc, scf, zf, out);
}

// Round 13
// 203.078 us; speedup vs baseline: 2.1052x; 2.1052x over previous
//
#include <hip/hip_runtime.h>
#include <math.h>

// Problem constants (from reference setup_inputs)
namespace {
constexpr int B = 128;
constexpr int T = 2048;
constexpr int D = 128;
constexpr int P = 64;
constexpr int TOUT = T + P;          // 2112
constexpr int NC = 64;               // chunks along T (isolated re-test on lean R9 kC)
constexpr int L = T / NC;            // 32 per chunk
constexpr float ALPHA = 0.94f;
constexpr float OMA = (float)(1.0 - 0.94);   // 1-alpha
constexpr float OMA_HALF = 0.03f;            // 0.5*(1-alpha)
constexpr float UCLIP = 1e-6f;
constexpr float INV_SQRT2 = 0.70710678118654752f;
}

// ---------------------------------------------------------------------------
// Direct composite map z = ndtri(student_t4_cdf(t)) = t * h(t^2), with
// h(q) a degree-4 polynomial in rc = 1/(8+q). Valid for q in [0, 33.34]
// (provable: ewma >= (1-alpha)(x-mu)^2 ==> t^2 <= 2/(1-alpha)).
// Max z err ~6e-3 vs 0.765 threshold; reference's u-clip never triggers.
// (Verified passing R9/R10/R12, absmax 0.015625.)
// ---------------------------------------------------------------------------
__device__ __forceinline__ float t_to_z_direct(float y, float vv) {
    float it = __builtin_amdgcn_rsqf(vv);     // 1/scale
    float t  = y * it;                        // student-t variate
    float q  = t * t;                         // in [0, 33.34]
    float rc = __builtin_amdgcn_rcpf(8.0f + q);
    float p;
    p = fmaf(-1453.744128f, rc, 610.201088f); // b4, b3  (8^k-scaled)
    p = fmaf(p, rc, -98.038976f);             // b2
    p = fmaf(p, rc, 10.835976f);              // b1
    p = fmaf(p, rc, 0.280213f);               // b0
    return t * p;
}

// ---------------------------------------------------------------------------
// Kernel A: per (b, chunk) — partial sum of x (for the mean) + chunk-local
// EWMA tails of x and x^2 with zero carry-in (chunk 0 uses true init).
// Scalar lanes (1 elem/thread) — measured fastest layout.
// ---------------------------------------------------------------------------
__global__ __launch_bounds__(128) void kA(const float* __restrict__ x,
                                          float* __restrict__ Spart,
                                          float* __restrict__ l1e,
                                          float* __restrict__ l2e) {
    const int c = blockIdx.x;      // chunk
    const int b = blockIdx.y;      // batch
    const int d = threadIdx.x;     // feature

    const float* xp = x + ((size_t)b * T + (size_t)c * L) * D + d;

    float x0 = xp[0];
    float sum = x0;
    float l1, l2;
    if (c == 0) { l1 = x0;        l2 = x0 * x0; }
    else        { l1 = OMA * x0;  l2 = OMA * (x0 * x0); }

    for (int k = 1; k < L; ++k) {
        float xv = xp[(size_t)k * D];
        sum += xv;
        l1 = fmaf(ALPHA, l1, OMA * xv);
        l2 = fmaf(ALPHA, l2, OMA * (xv * xv));
    }

    const size_t o = ((size_t)b * NC + c) * D + d;
    Spart[o] = sum;
    l1e[o]   = l1;
    l2e[o]   = l2;
}

// ---------------------------------------------------------------------------
// Kernel B: per (b,d) — stitch chunk carries exactly:
//   E_end[c] = l_end[c] + alpha^L * E_end[c-1]
// Pass 2 rewrites the HALF combined carry crw_half = 0.5*c2 - mu*c1
// into carry1. carry1 aliases Spart, carry2 aliases l1e (same-thread
// load-before-store) — NO __restrict__ there.
// ---------------------------------------------------------------------------
__global__ __launch_bounds__(256) void kB(const float* Spart,
                                          const float* l1e,
                                          const float* l2e,
                                          float* carry1,
                                          float* carry2,
                                          float* __restrict__ loc,
                                          float* __restrict__ scf) {
    const int tid = blockIdx.x * blockDim.x + threadIdx.x;   // b*D + d
    if (tid >= B * D) return;
    const int b = tid / D;
    const int d = tid % D;

    const float alphaL = (float)pow((double)ALPHA, (double)L);  // folded

    float sum = 0.0f, e1 = 0.0f, e2 = 0.0f;
    for (int c = 0; c < NC; ++c) {
        const size_t o = ((size_t)b * NC + c) * D + d;
        float sp = Spart[o];
        float t1 = l1e[o];
        float t2 = l2e[o];
        carry1[o] = e1;
        carry2[o] = e2;
        sum += sp;
        e1 = t1 + alphaL * e1;
        e2 = t2 + alphaL * e2;
    }

    const float mu = sum * (1.0f / (float)T);
    loc[tid] = mu;
    float ew = fmaxf(fmaf(mu, mu, fmaf(-2.0f * mu, e1, e2)), 0.0f);
    scf[tid] = fmaxf(sqrtf(0.5f * ew), 1e-5f);

    // fold carries: crw_half = 0.5*c2 - mu*c1 (stored into carry1)
    for (int c = 0; c < NC; ++c) {
        const size_t o = ((size_t)b * NC + c) * D + d;
        float c1 = carry1[o];
        float c2 = carry2[o];
        carry1[o] = fmaf(-mu, c1, 0.5f * c2);
    }
}

// ---------------------------------------------------------------------------
// Kernel C: per (b, chunk) — single fused EWMA scan of the 0.5-scaled
// variable (R9 structure, identical math), NT stores; the c == NC-1 blocks
// append the P=64 forecast rows (old kD; numerics validated R10/R12).
// ---------------------------------------------------------------------------
__global__ __launch_bounds__(128) void kC(const float* __restrict__ x,
                                          const float* __restrict__ crwb,
                                          const float* __restrict__ locg,
                                          const float* __restrict__ scfg,
                                          const float* __restrict__ zf,
                                          float* __restrict__ out) {
    const int c = blockIdx.x;
    const int b = blockIdx.y;
    const int d = threadIdx.x;

    const size_t co = ((size_t)b * NC + c) * D + d;
    const float crw   = crwb[co];              // 0.5-scaled folded carry
    const float mu    = locg[b * D + d];
    const float twomu = 2.0f * mu;
    const float mu2h  = 0.5f * mu * mu;

    const float* xp = x   + ((size_t)b * T    + (size_t)c * L) * D + d;
    float*       op = out + ((size_t)b * TOUT + (size_t)c * L) * D + d;

    float xv = xp[0];
    float g  = xv * (xv - twomu);
    float base = (c == 0) ? 0.5f * g : OMA_HALF * g;
    float s  = fmaf(ALPHA, crw, base);
    float vv = fmaxf(s + mu2h, 1e-10f);
    __builtin_nontemporal_store(t_to_z_direct(xv - mu, vv), &op[0]);

    for (int k = 1; k < L; ++k) {
        xv = xp[(size_t)k * D];
        g  = xv * (xv - twomu);
        s  = fmaf(ALPHA, s, OMA_HALF * g);
        vv = fmaxf(s + mu2h, 1e-10f);
        __builtin_nontemporal_store(t_to_z_direct(xv - mu, vv), &op[(size_t)k * D]);
    }

    // ---- forecasts (old kD) on the c == NC-1 blocks ----
    if (c == NC - 1) {
        const float sc = scfg[b * D + d];
        const float* zp = zf  + (size_t)b * P * D + d;
        float*       fp = out + ((size_t)b * TOUT + T) * D + d;

        for (int p = 0; p < P; ++p) {
            float zv = zp[(size_t)p * D];
            float u = 0.5f * erfcf(-zv * INV_SQRT2);            // ndtr
            u = fminf(fmaxf(u, UCLIP), 1.0f - UCLIP);

            float a = 4.0f * u * (1.0f - u);
            a = fminf(fmaxf(a, UCLIP), 1.0f);
            float sa = sqrtf(a);
            float inner = cosf(acosf(sa) * (1.0f / 3.0f)) / sa - 1.0f;
            float qv = 2.0f * sqrtf(fmaxf(inner, 0.0f));

            float sgn = (u > 0.5f) ? 1.0f : ((u < 0.5f) ? -1.0f : 0.0f);
            float val = fmaf(sgn * qv, sc, mu);

            __builtin_nontemporal_store(val, &fp[(size_t)p * D]);
        }
    }
}

// ---------------------------------------------------------------------------
extern "C" void kernel_launch(void* const* d_in, const int* in_sizes, int n_in,
                              void* d_out, int out_size, void* d_ws, size_t ws_size,
                              hipStream_t stream) {
    const float* x  = (const float*)d_in[0];   // (B,T,D)
    const float* zf = (const float*)d_in[1];   // (B,P,D)
    float* out = (float*)d_out;                // (B,T+P,D)

    float* ws = (float*)d_ws;
    const size_t NCH = (size_t)B * NC * D;     // 1048576
    float* Spart  = ws;                        // reused as carry1 / crw_half
    float* l1e    = Spart + NCH;               // reused as carry2
    float* l2e    = l1e + NCH;
    float* loc    = l2e + NCH;                 // B*D
    float* scf    = loc + (size_t)B * D;       // B*D
    float* carry1 = Spart;                     // alias (see kB)
    float* carry2 = l1e;                       // alias (see kB)

    kA<<<dim3(NC, B), 128, 0, stream>>>(x, Spart, l1e, l2e);
    kB<<<(B * D + 255) / 256, 256, 0, stream>>>(Spart, l1e, l2e, carry1, carry2, loc, scf);
    kC<<<dim3(NC, B), 128, 0, stream>>>(x, Spart, loc, scf, zf, out);
}

// Round 14
// 92.174 us; speedup vs baseline: 4.6382x; 2.2032x over previous
//
#include <hip/hip_runtime.h>
#include <math.h>

// Problem constants (from reference setup_inputs)
namespace {
constexpr int B = 128;
constexpr int T = 2048;
constexpr int D = 128;
constexpr int P = 64;
constexpr int TOUT = T + P;          // 2112
constexpr int NC = 64;               // chunks along T
constexpr int L = T / NC;            // 32 per chunk
constexpr float ALPHA = 0.94f;
constexpr float OMA = (float)(1.0 - 0.94);   // 1-alpha
constexpr float OMA_HALF = 0.03f;            // 0.5*(1-alpha)
constexpr float UCLIP = 1e-6f;
constexpr float INV_SQRT2 = 0.70710678118654752f;
}

// ---------------------------------------------------------------------------
// Direct composite map z = ndtri(student_t4_cdf(t)) = t * h(t^2), with
// h(q) a degree-4 polynomial in rc = 1/(8+q). Valid for q in [0, 33.34]
// (provable: ewma >= (1-alpha)(x-mu)^2 ==> t^2 <= 2/(1-alpha)).
// Max z err ~6e-3 vs 0.765 threshold. (Verified R9/R10/R12/R13, absmax
// 0.015625.)
// ---------------------------------------------------------------------------
__device__ __forceinline__ float t_to_z_direct(float y, float vv) {
    float it = __builtin_amdgcn_rsqf(vv);     // 1/scale
    float t  = y * it;                        // student-t variate
    float q  = t * t;                         // in [0, 33.34]
    float rc = __builtin_amdgcn_rcpf(8.0f + q);
    float p;
    p = fmaf(-1453.744128f, rc, 610.201088f); // b4, b3  (8^k-scaled)
    p = fmaf(p, rc, -98.038976f);             // b2
    p = fmaf(p, rc, 10.835976f);              // b1
    p = fmaf(p, rc, 0.280213f);               // b0
    return t * p;
}

// ---------------------------------------------------------------------------
// Kernel A: per (chunk, batch-pair) — each thread runs TWO independent
// chunk-chains (batches 2y and 2y+1) for doubled memory-level parallelism
// (kC is load-latency-bound; two loads in flight per thread).
// ---------------------------------------------------------------------------
__global__ __launch_bounds__(128) void kA(const float* __restrict__ x,
                                          float* __restrict__ Spart,
                                          float* __restrict__ l1e,
                                          float* __restrict__ l2e) {
    const int c  = blockIdx.x;     // chunk
    const int b0 = blockIdx.y * 2; // batch pair
    const int b1 = b0 + 1;
    const int d  = threadIdx.x;    // feature

    const float* xp0 = x + ((size_t)b0 * T + (size_t)c * L) * D + d;
    const float* xp1 = x + ((size_t)b1 * T + (size_t)c * L) * D + d;

    float xv0 = xp0[0], xv1 = xp1[0];
    float sum0 = xv0, sum1 = xv1;
    float l10, l20, l11, l21;
    if (c == 0) {
        l10 = xv0;       l20 = xv0 * xv0;
        l11 = xv1;       l21 = xv1 * xv1;
    } else {
        l10 = OMA * xv0; l20 = OMA * (xv0 * xv0);
        l11 = OMA * xv1; l21 = OMA * (xv1 * xv1);
    }

    for (int k = 1; k < L; ++k) {
        xv0 = xp0[(size_t)k * D];
        xv1 = xp1[(size_t)k * D];
        sum0 += xv0;
        sum1 += xv1;
        l10 = fmaf(ALPHA, l10, OMA * xv0);
        l20 = fmaf(ALPHA, l20, OMA * (xv0 * xv0));
        l11 = fmaf(ALPHA, l11, OMA * xv1);
        l21 = fmaf(ALPHA, l21, OMA * (xv1 * xv1));
    }

    const size_t o0 = ((size_t)b0 * NC + c) * D + d;
    const size_t o1 = ((size_t)b1 * NC + c) * D + d;
    Spart[o0] = sum0;  l1e[o0] = l10;  l2e[o0] = l20;
    Spart[o1] = sum1;  l1e[o1] = l11;  l2e[o1] = l21;
}

// ---------------------------------------------------------------------------
// Kernel B: per (b,d) — stitch chunk carries exactly (R9 structure, NC=64):
//   E_end[c] = l_end[c] + alpha^L * E_end[c-1]
// Pass 2 rewrites crw_half = 0.5*c2 - mu*c1 into carry1.
// carry1 aliases Spart, carry2 aliases l1e (same-thread load-before-store)
// — NO __restrict__ there.
// ---------------------------------------------------------------------------
__global__ __launch_bounds__(256) void kB(const float* Spart,
                                          const float* l1e,
                                          const float* l2e,
                                          float* carry1,
                                          float* carry2,
                                          float* __restrict__ loc,
                                          float* __restrict__ scf) {
    const int tid = blockIdx.x * blockDim.x + threadIdx.x;   // b*D + d
    if (tid >= B * D) return;
    const int b = tid / D;
    const int d = tid % D;

    const float alphaL = (float)pow((double)ALPHA, (double)L);  // folded

    float sum = 0.0f, e1 = 0.0f, e2 = 0.0f;
    for (int c = 0; c < NC; ++c) {
        const size_t o = ((size_t)b * NC + c) * D + d;
        float sp = Spart[o];
        float t1 = l1e[o];
        float t2 = l2e[o];
        carry1[o] = e1;
        carry2[o] = e2;
        sum += sp;
        e1 = t1 + alphaL * e1;
        e2 = t2 + alphaL * e2;
    }

    const float mu = sum * (1.0f / (float)T);
    loc[tid] = mu;
    float ew = fmaxf(fmaf(mu, mu, fmaf(-2.0f * mu, e1, e2)), 0.0f);
    scf[tid] = fmaxf(sqrtf(0.5f * ew), 1e-5f);

    // fold carries: crw_half = 0.5*c2 - mu*c1 (stored into carry1)
    for (int c = 0; c < NC; ++c) {
        const size_t o = ((size_t)b * NC + c) * D + d;
        float c1 = carry1[o];
        float c2 = carry2[o];
        carry1[o] = fmaf(-mu, c1, 0.5f * c2);
    }
}

// ---------------------------------------------------------------------------
// Kernel C: per (chunk, batch-pair) — TWO independent fused EWMA scans per
// thread (batches 2y, 2y+1): doubled loads-in-flight hides LLC/HBM latency.
//   s_k = alpha*s_{k-1} + 0.5(1-alpha)*x*(x-2mu);  s_0 = base + alpha*crw
//   vv = max(s + 0.5*mu^2, 1e-10);  z = t*h(t^2) direct
// NT stores keep x LLC-resident (R5's win). NO kD fold (R13 lesson: the
// folded forecast tail serialized 1M threads' work onto 128 blocks).
// ---------------------------------------------------------------------------
__global__ __launch_bounds__(128) void kC(const float* __restrict__ x,
                                          const float* __restrict__ crwb,
                                          const float* __restrict__ locg,
                                          float* __restrict__ out) {
    const int c  = blockIdx.x;
    const int b0 = blockIdx.y * 2;
    const int b1 = b0 + 1;
    const int d  = threadIdx.x;

    const size_t co0 = ((size_t)b0 * NC + c) * D + d;
    const size_t co1 = ((size_t)b1 * NC + c) * D + d;
    const float crw0 = crwb[co0];
    const float crw1 = crwb[co1];
    const float mu0  = locg[b0 * D + d];
    const float mu1  = locg[b1 * D + d];
    const float twomu0 = 2.0f * mu0, mu2h0 = 0.5f * mu0 * mu0;
    const float twomu1 = 2.0f * mu1, mu2h1 = 0.5f * mu1 * mu1;

    const float* xp0 = x   + ((size_t)b0 * T    + (size_t)c * L) * D + d;
    const float* xp1 = x   + ((size_t)b1 * T    + (size_t)c * L) * D + d;
    float*       op0 = out + ((size_t)b0 * TOUT + (size_t)c * L) * D + d;
    float*       op1 = out + ((size_t)b1 * TOUT + (size_t)c * L) * D + d;

    float xv0 = xp0[0], xv1 = xp1[0];
    float g0 = xv0 * (xv0 - twomu0);
    float g1 = xv1 * (xv1 - twomu1);
    float base0 = (c == 0) ? 0.5f * g0 : OMA_HALF * g0;
    float base1 = (c == 0) ? 0.5f * g1 : OMA_HALF * g1;
    float s0 = fmaf(ALPHA, crw0, base0);
    float s1 = fmaf(ALPHA, crw1, base1);
    float vv0 = fmaxf(s0 + mu2h0, 1e-10f);
    float vv1 = fmaxf(s1 + mu2h1, 1e-10f);
    __builtin_nontemporal_store(t_to_z_direct(xv0 - mu0, vv0), &op0[0]);
    __builtin_nontemporal_store(t_to_z_direct(xv1 - mu1, vv1), &op1[0]);

    for (int k = 1; k < L; ++k) {
        xv0 = xp0[(size_t)k * D];
        xv1 = xp1[(size_t)k * D];
        g0 = xv0 * (xv0 - twomu0);
        g1 = xv1 * (xv1 - twomu1);
        s0 = fmaf(ALPHA, s0, OMA_HALF * g0);
        s1 = fmaf(ALPHA, s1, OMA_HALF * g1);
        vv0 = fmaxf(s0 + mu2h0, 1e-10f);
        vv1 = fmaxf(s1 + mu2h1, 1e-10f);
        __builtin_nontemporal_store(t_to_z_direct(xv0 - mu0, vv0), &op0[(size_t)k * D]);
        __builtin_nontemporal_store(t_to_z_direct(xv1 - mu1, vv1), &op1[(size_t)k * D]);
    }
}

// ---------------------------------------------------------------------------
// Kernel D: forecasts — standalone 1-elem/thread (R13 lesson), NT stores.
// ---------------------------------------------------------------------------
__global__ __launch_bounds__(256) void kD(const float* __restrict__ zf,
                                          const float* __restrict__ loc,
                                          const float* __restrict__ scf,
                                          float* __restrict__ out) {
    const int idx = blockIdx.x * blockDim.x + threadIdx.x;
    if (idx >= B * P * D) return;
    const int d  = idx % D;
    const int bp = idx / D;
    const int p  = bp % P;
    const int b  = bp / P;

    float zv = zf[idx];
    float u = 0.5f * erfcf(-zv * INV_SQRT2);            // ndtr
    u = fminf(fmaxf(u, UCLIP), 1.0f - UCLIP);

    float a = 4.0f * u * (1.0f - u);
    a = fminf(fmaxf(a, UCLIP), 1.0f);
    float sa = sqrtf(a);
    float inner = cosf(acosf(sa) * (1.0f / 3.0f)) / sa - 1.0f;
    float qv = 2.0f * sqrtf(fmaxf(inner, 0.0f));

    float sgn = (u > 0.5f) ? 1.0f : ((u < 0.5f) ? -1.0f : 0.0f);
    float val = sgn * qv * scf[b * D + d] + loc[b * D + d];

    __builtin_nontemporal_store(val, &out[((size_t)b * TOUT + T + p) * D + d]);
}

// ---------------------------------------------------------------------------
extern "C" void kernel_launch(void* const* d_in, const int* in_sizes, int n_in,
                              void* d_out, int out_size, void* d_ws, size_t ws_size,
                              hipStream_t stream) {
    const float* x  = (const float*)d_in[0];   // (B,T,D)
    const float* zf = (const float*)d_in[1];   // (B,P,D)
    float* out = (float*)d_out;                // (B,T+P,D)

    float* ws = (float*)d_ws;
    const size_t NCH = (size_t)B * NC * D;     // 1048576
    float* Spart  = ws;                        // reused as carry1 / crw_half
    float* l1e    = Spart + NCH;               // reused as carry2
    float* l2e    = l1e + NCH;
    float* loc    = l2e + NCH;                 // B*D
    float* scf    = loc + (size_t)B * D;       // B*D
    float* carry1 = Spart;                     // alias (see kB)
    float* carry2 = l1e;                       // alias (see kB)

    kA<<<dim3(NC, B / 2), 128, 0, stream>>>(x, Spart, l1e, l2e);
    kB<<<(B * D + 255) / 256, 256, 0, stream>>>(Spart, l1e, l2e, carry1, carry2, loc, scf);
    kC<<<dim3(NC, B / 2), 128, 0, stream>>>(x, Spart, loc, out);
    kD<<<(B * P * D + 255) / 256, 256, 0, stream>>>(zf, loc, scf, out);
}

// Round 15
// 83.538 us; speedup vs baseline: 5.1177x; 1.1034x over previous
//
#include <hip/hip_runtime.h>
#include <math.h>

// Problem constants (from reference setup_inputs)
namespace {
constexpr int B = 128;
constexpr int T = 2048;
constexpr int D = 128;
constexpr int P = 64;
constexpr int TOUT = T + P;          // 2112
constexpr int NC = 32;               // chunks along T (best measured: R9)
constexpr int L = T / NC;            // 64 per chunk
constexpr float ALPHA = 0.94f;
constexpr float OMA = (float)(1.0 - 0.94);   // 1-alpha
constexpr float OMA_HALF = 0.03f;            // 0.5*(1-alpha)
constexpr float UCLIP = 1e-6f;
constexpr float INV_SQRT2 = 0.70710678118654752f;
}

// ---------------------------------------------------------------------------
// Direct composite map z = ndtri(student_t4_cdf(t)) = t * h(t^2), with
// h(q) a degree-4 polynomial in rc = 1/(8+q). Valid for q in [0, 33.34]
// (provable: ewma >= (1-alpha)(x-mu)^2 ==> t^2 <= 2/(1-alpha)).
// Max z err ~6e-3 vs 0.765 threshold. (Verified R9-R14, absmax 0.015625.)
// ---------------------------------------------------------------------------
__device__ __forceinline__ float t_to_z_direct(float y, float vv) {
    float it = __builtin_amdgcn_rsqf(vv);     // 1/scale
    float t  = y * it;                        // student-t variate
    float q  = t * t;                         // in [0, 33.34]
    float rc = __builtin_amdgcn_rcpf(8.0f + q);
    float p;
    p = fmaf(-1453.744128f, rc, 610.201088f); // b4, b3  (8^k-scaled)
    p = fmaf(p, rc, -98.038976f);             // b2
    p = fmaf(p, rc, 10.835976f);              // b1
    p = fmaf(p, rc, 0.280213f);               // b0
    return t * p;
}

// ---------------------------------------------------------------------------
// Kernel A: per (b, chunk) — partial sum of x (for the mean) + chunk-local
// EWMA tails of x and x^2 with zero carry-in (chunk 0 uses true init).
// (Identical to R9 — scalar lanes, fastest measured.)
// ---------------------------------------------------------------------------
__global__ __launch_bounds__(128) void kA(const float* __restrict__ x,
                                          float* __restrict__ Spart,
                                          float* __restrict__ l1e,
                                          float* __restrict__ l2e) {
    const int c = blockIdx.x;      // chunk
    const int b = blockIdx.y;      // batch
    const int d = threadIdx.x;     // feature

    const float* xp = x + ((size_t)b * T + (size_t)c * L) * D + d;

    float x0 = xp[0];
    float sum = x0;
    float l1, l2;
    if (c == 0) { l1 = x0;        l2 = x0 * x0; }
    else        { l1 = OMA * x0;  l2 = OMA * (x0 * x0); }

    for (int k = 1; k < L; ++k) {
        float xv = xp[(size_t)k * D];
        sum += xv;
        l1 = fmaf(ALPHA, l1, OMA * xv);
        l2 = fmaf(ALPHA, l2, OMA * (xv * xv));
    }

    const size_t o = ((size_t)b * NC + c) * D + d;
    Spart[o] = sum;
    l1e[o]   = l1;
    l2e[o]   = l2;
}

// ---------------------------------------------------------------------------
// Kernel B: per (b,d) — stitch chunk carries exactly (identical to R9):
//   E_end[c] = l_end[c] + alpha^L * E_end[c-1]
// Pass 2 rewrites crw_half = 0.5*c2 - mu*c1 into carry1.
// carry1 aliases Spart, carry2 aliases l1e (same-thread load-before-store)
// — NO __restrict__ there.
// ---------------------------------------------------------------------------
__global__ __launch_bounds__(256) void kB(const float* Spart,
                                          const float* l1e,
                                          const float* l2e,
                                          float* carry1,
                                          float* carry2,
                                          float* __restrict__ loc,
                                          float* __restrict__ scf) {
    const int tid = blockIdx.x * blockDim.x + threadIdx.x;   // b*D + d
    if (tid >= B * D) return;
    const int b = tid / D;
    const int d = tid % D;

    const float alphaL = (float)pow((double)ALPHA, (double)L);  // folded

    float sum = 0.0f, e1 = 0.0f, e2 = 0.0f;
    for (int c = 0; c < NC; ++c) {
        const size_t o = ((size_t)b * NC + c) * D + d;
        float sp = Spart[o];
        float t1 = l1e[o];
        float t2 = l2e[o];
        carry1[o] = e1;
        carry2[o] = e2;
        sum += sp;
        e1 = t1 + alphaL * e1;
        e2 = t2 + alphaL * e2;
    }

    const float mu = sum * (1.0f / (float)T);
    loc[tid] = mu;
    float ew = fmaxf(fmaf(mu, mu, fmaf(-2.0f * mu, e1, e2)), 0.0f);
    scf[tid] = fmaxf(sqrtf(0.5f * ew), 1e-5f);

    // fold carries: crw_half = 0.5*c2 - mu*c1 (stored into carry1)
    for (int c = 0; c < NC; ++c) {
        const size_t o = ((size_t)b * NC + c) * D + d;
        float c1 = carry1[o];
        float c2 = carry2[o];
        carry1[o] = fmaf(-mu, c1, 0.5f * c2);
    }
}

// ---------------------------------------------------------------------------
// Kernel C: THE ONE CHANGE vs R9 — two batches per thread (b0=2y, b1=2y+1):
// two independent load streams + two independent scan/transform chains
// double per-thread memory-level parallelism at identical wave count.
// Math per chain identical to R9. NT stores (R5's win).
// ---------------------------------------------------------------------------
__global__ __launch_bounds__(128) void kC(const float* __restrict__ x,
                                          const float* __restrict__ crwb,
                                          const float* __restrict__ locg,
                                          float* __restrict__ out) {
    const int c  = blockIdx.x;
    const int b0 = blockIdx.y * 2;
    const int b1 = b0 + 1;
    const int d  = threadIdx.x;

    const size_t co0 = ((size_t)b0 * NC + c) * D + d;
    const size_t co1 = ((size_t)b1 * NC + c) * D + d;
    const float crw0 = crwb[co0];
    const float crw1 = crwb[co1];
    const float mu0  = locg[b0 * D + d];
    const float mu1  = locg[b1 * D + d];
    const float twomu0 = 2.0f * mu0, mu2h0 = 0.5f * mu0 * mu0;
    const float twomu1 = 2.0f * mu1, mu2h1 = 0.5f * mu1 * mu1;

    const float* xp0 = x   + ((size_t)b0 * T    + (size_t)c * L) * D + d;
    const float* xp1 = x   + ((size_t)b1 * T    + (size_t)c * L) * D + d;
    float*       op0 = out + ((size_t)b0 * TOUT + (size_t)c * L) * D + d;
    float*       op1 = out + ((size_t)b1 * TOUT + (size_t)c * L) * D + d;

    float xv0 = xp0[0], xv1 = xp1[0];
    float g0 = xv0 * (xv0 - twomu0);
    float g1 = xv1 * (xv1 - twomu1);
    float base0 = (c == 0) ? 0.5f * g0 : OMA_HALF * g0;
    float base1 = (c == 0) ? 0.5f * g1 : OMA_HALF * g1;
    float s0 = fmaf(ALPHA, crw0, base0);
    float s1 = fmaf(ALPHA, crw1, base1);
    float vv0 = fmaxf(s0 + mu2h0, 1e-10f);
    float vv1 = fmaxf(s1 + mu2h1, 1e-10f);
    __builtin_nontemporal_store(t_to_z_direct(xv0 - mu0, vv0), &op0[0]);
    __builtin_nontemporal_store(t_to_z_direct(xv1 - mu1, vv1), &op1[0]);

    for (int k = 1; k < L; ++k) {
        xv0 = xp0[(size_t)k * D];
        xv1 = xp1[(size_t)k * D];
        g0 = xv0 * (xv0 - twomu0);
        g1 = xv1 * (xv1 - twomu1);
        s0 = fmaf(ALPHA, s0, OMA_HALF * g0);
        s1 = fmaf(ALPHA, s1, OMA_HALF * g1);
        vv0 = fmaxf(s0 + mu2h0, 1e-10f);
        vv1 = fmaxf(s1 + mu2h1, 1e-10f);
        __builtin_nontemporal_store(t_to_z_direct(xv0 - mu0, vv0), &op0[(size_t)k * D]);
        __builtin_nontemporal_store(t_to_z_direct(xv1 - mu1, vv1), &op1[(size_t)k * D]);
    }
}

// ---------------------------------------------------------------------------
// Kernel D: forecasts — standalone 1-elem/thread (identical to R9).
// ---------------------------------------------------------------------------
__global__ __launch_bounds__(256) void kD(const float* __restrict__ zf,
                                          const float* __restrict__ loc,
                                          const float* __restrict__ scf,
                                          float* __restrict__ out) {
    const int idx = blockIdx.x * blockDim.x + threadIdx.x;
    if (idx >= B * P * D) return;
    const int d  = idx % D;
    const int bp = idx / D;
    const int p  = bp % P;
    const int b  = bp / P;

    float zv = zf[idx];
    float u = 0.5f * erfcf(-zv * INV_SQRT2);            // ndtr
    u = fminf(fmaxf(u, UCLIP), 1.0f - UCLIP);

    float a = 4.0f * u * (1.0f - u);
    a = fminf(fmaxf(a, UCLIP), 1.0f);
    float sa = sqrtf(a);
    float inner = cosf(acosf(sa) * (1.0f / 3.0f)) / sa - 1.0f;
    float qv = 2.0f * sqrtf(fmaxf(inner, 0.0f));

    float sgn = (u > 0.5f) ? 1.0f : ((u < 0.5f) ? -1.0f : 0.0f);
    float val = sgn * qv * scf[b * D + d] + loc[b * D + d];

    __builtin_nontemporal_store(val, &out[((size_t)b * TOUT + T + p) * D + d]);
}

// ---------------------------------------------------------------------------
extern "C" void kernel_launch(void* const* d_in, const int* in_sizes, int n_in,
                              void* d_out, int out_size, void* d_ws, size_t ws_size,
                              hipStream_t stream) {
    const float* x  = (const float*)d_in[0];   // (B,T,D)
    const float* zf = (const float*)d_in[1];   // (B,P,D)
    float* out = (float*)d_out;                // (B,T+P,D)

    float* ws = (float*)d_ws;
    const size_t NCH = (size_t)B * NC * D;     // 524288
    float* Spart  = ws;                        // reused as carry1 / crw_half
    float* l1e    = Spart + NCH;               // reused as carry2
    float* l2e    = l1e + NCH;
    float* loc    = l2e + NCH;                 // B*D
    float* scf    = loc + (size_t)B * D;       // B*D
    float* carry1 = Spart;                     // alias (see kB)
    float* carry2 = l1e;                       // alias (see kB)

    kA<<<dim3(NC, B), 128, 0, stream>>>(x, Spart, l1e, l2e);
    kB<<<(B * D + 255) / 256, 256, 0, stream>>>(Spart, l1e, l2e, carry1, carry2, loc, scf);
    kC<<<dim3(NC, B / 2), 128, 0, stream>>>(x, Spart, loc, out);
    kD<<<(B * P * D + 255) / 256, 256, 0, stream>>>(zf, loc, scf, out);
}

// Round 16
// 77.789 us; speedup vs baseline: 5.4959x; 1.0739x over previous
//
#include <hip/hip_runtime.h>
#include <math.h>

// Problem constants (from reference setup_inputs)
namespace {
constexpr int B = 128;
constexpr int T = 2048;
constexpr int D = 128;
constexpr int P = 64;
constexpr int TOUT = T + P;          // 2112
constexpr int NC = 32;               // chunks along T (best measured: R9)
constexpr int L = T / NC;            // 64 per chunk
constexpr int FB = 8;                // forecast blocks per batch (kD folded)
constexpr float ALPHA = 0.94f;
constexpr float OMA = (float)(1.0 - 0.94);   // 1-alpha
constexpr float OMA_HALF = 0.03f;            // 0.5*(1-alpha)
constexpr float UCLIP = 1e-6f;
constexpr float INV_SQRT2 = 0.70710678118654752f;
}

// ---------------------------------------------------------------------------
// Direct composite map z = ndtri(student_t4_cdf(t)) = t * h(t^2), with
// h(q) a degree-4 polynomial in rc = 1/(8+q). Valid for q in [0, 33.34]
// (provable: ewma >= (1-alpha)(x-mu)^2 ==> t^2 <= 2/(1-alpha)).
// Max z err ~6e-3 vs 0.765 threshold. (Verified R9-R15, absmax 0.015625.)
// ---------------------------------------------------------------------------
__device__ __forceinline__ float t_to_z_direct(float y, float vv) {
    float it = __builtin_amdgcn_rsqf(vv);     // 1/scale
    float t  = y * it;                        // student-t variate
    float q  = t * t;                         // in [0, 33.34]
    float rc = __builtin_amdgcn_rcpf(8.0f + q);
    float p;
    p = fmaf(-1453.744128f, rc, 610.201088f); // b4, b3  (8^k-scaled)
    p = fmaf(p, rc, -98.038976f);             // b2
    p = fmaf(p, rc, 10.835976f);              // b1
    p = fmaf(p, rc, 0.280213f);               // b0
    return t * p;
}

// ---------------------------------------------------------------------------
// Kernel A: per (b, chunk) — partial sum of x (for the mean) + chunk-local
// EWMA tails of x and x^2 with zero carry-in (chunk 0 uses true init).
// (Identical to R9 — scalar lanes, fastest measured.)
// ---------------------------------------------------------------------------
__global__ __launch_bounds__(128) void kA(const float* __restrict__ x,
                                          float* __restrict__ Spart,
                                          float* __restrict__ l1e,
                                          float* __restrict__ l2e) {
    const int c = blockIdx.x;      // chunk
    const int b = blockIdx.y;      // batch
    const int d = threadIdx.x;     // feature

    const float* xp = x + ((size_t)b * T + (size_t)c * L) * D + d;

    float x0 = xp[0];
    float sum = x0;
    float l1, l2;
    if (c == 0) { l1 = x0;        l2 = x0 * x0; }
    else        { l1 = OMA * x0;  l2 = OMA * (x0 * x0); }

    for (int k = 1; k < L; ++k) {
        float xv = xp[(size_t)k * D];
        sum += xv;
        l1 = fmaf(ALPHA, l1, OMA * xv);
        l2 = fmaf(ALPHA, l2, OMA * (xv * xv));
    }

    const size_t o = ((size_t)b * NC + c) * D + d;
    Spart[o] = sum;
    l1e[o]   = l1;
    l2e[o]   = l2;
}

// ---------------------------------------------------------------------------
// Kernel B: per (b,d) — stitch chunk carries, ONE pass only (the fold moved
// into kC: 1 fma/thread there vs 36 MB of L2 traffic here).
//   E_end[c] = l_end[c] + alpha^L * E_end[c-1]
// carry1 aliases Spart, carry2 aliases l1e (same-thread load-before-store)
// — NO __restrict__ there.
// ---------------------------------------------------------------------------
__global__ __launch_bounds__(256) void kB(const float* Spart,
                                          const float* l1e,
                                          const float* l2e,
                                          float* carry1,
                                          float* carry2,
                                          float* __restrict__ loc,
                                          float* __restrict__ scf) {
    const int tid = blockIdx.x * blockDim.x + threadIdx.x;   // b*D + d
    if (tid >= B * D) return;
    const int b = tid / D;
    const int d = tid % D;

    const float alphaL = (float)pow((double)ALPHA, (double)L);  // folded

    float sum = 0.0f, e1 = 0.0f, e2 = 0.0f;
    for (int c = 0; c < NC; ++c) {
        const size_t o = ((size_t)b * NC + c) * D + d;
        float sp = Spart[o];
        float t1 = l1e[o];
        float t2 = l2e[o];
        carry1[o] = e1;
        carry2[o] = e2;
        sum += sp;
        e1 = t1 + alphaL * e1;
        e2 = t2 + alphaL * e2;
    }

    const float mu = sum * (1.0f / (float)T);
    loc[tid] = mu;
    float ew = fmaxf(fmaf(mu, mu, fmaf(-2.0f * mu, e1, e2)), 0.0f);
    scf[tid] = fmaxf(sqrtf(0.5f * ew), 1e-5f);
}

// ---------------------------------------------------------------------------
// Kernel C: grid (NC+FB, B).
//   Blocks c < NC: single fused EWMA scan (R9 math), carry fold done
//     locally (crw = 0.5*c2 - mu*c1, one fma), NT stores.
//   Blocks c >= NC: forecast blocks (old kD), 8 per batch, 8 coalesced
//     elements per thread — run concurrently with the scan blocks, removing
//     kD's dispatch boundary. (R13's serial-tail mistake avoided: these are
//     dedicated short blocks, not appended to busy scan blocks.)
// ---------------------------------------------------------------------------
__global__ __launch_bounds__(128) void kC(const float* __restrict__ x,
                                          const float* __restrict__ carry1,
                                          const float* __restrict__ carry2,
                                          const float* __restrict__ locg,
                                          const float* __restrict__ scfg,
                                          const float* __restrict__ zf,
                                          float* __restrict__ out) {
    const int c = blockIdx.x;
    const int b = blockIdx.y;
    const int d = threadIdx.x;

    if (c >= NC) {
        // ---- forecast block (old kD) ----
        const int f = c - NC;                       // 0..FB-1
        const float* zp = zf  + (size_t)b * P * D;
        float*       fp = out + ((size_t)b * TOUT + T) * D;
        #pragma unroll
        for (int i = 0; i < (P * D) / (FB * 128); ++i) {
            const int lin = f * 128 + d + i * (FB * 128);
            const int p  = lin >> 7;                // / D
            const int dd = lin & (D - 1);           // % D
            float zv = zp[lin];
            float u = 0.5f * erfcf(-zv * INV_SQRT2);            // ndtr
            u = fminf(fmaxf(u, UCLIP), 1.0f - UCLIP);
            float a = 4.0f * u * (1.0f - u);
            a = fminf(fmaxf(a, UCLIP), 1.0f);
            float sa = sqrtf(a);
            float inner = cosf(acosf(sa) * (1.0f / 3.0f)) / sa - 1.0f;
            float qv = 2.0f * sqrtf(fmaxf(inner, 0.0f));
            float sgn = (u > 0.5f) ? 1.0f : ((u < 0.5f) ? -1.0f : 0.0f);
            float val = fmaf(sgn * qv, scfg[b * D + dd], locg[b * D + dd]);
            __builtin_nontemporal_store(val, &fp[(size_t)p * D + dd]);
        }
        return;
    }

    // ---- scan block (R9 math; carry fold local) ----
    const size_t co = ((size_t)b * NC + c) * D + d;
    const float mu    = locg[b * D + d];
    const float crw   = fmaf(-mu, carry1[co], 0.5f * carry2[co]);
    const float twomu = 2.0f * mu;
    const float mu2h  = 0.5f * mu * mu;

    const float* xp = x   + ((size_t)b * T    + (size_t)c * L) * D + d;
    float*       op = out + ((size_t)b * TOUT + (size_t)c * L) * D + d;

    float xv = xp[0];
    float g  = xv * (xv - twomu);
    float base = (c == 0) ? 0.5f * g : OMA_HALF * g;
    float s  = fmaf(ALPHA, crw, base);
    float vv = fmaxf(s + mu2h, 1e-10f);
    __builtin_nontemporal_store(t_to_z_direct(xv - mu, vv), &op[0]);

    for (int k = 1; k < L; ++k) {
        xv = xp[(size_t)k * D];
        g  = xv * (xv - twomu);
        s  = fmaf(ALPHA, s, OMA_HALF * g);
        vv = fmaxf(s + mu2h, 1e-10f);
        __builtin_nontemporal_store(t_to_z_direct(xv - mu, vv), &op[(size_t)k * D]);
    }
}

// ---------------------------------------------------------------------------
extern "C" void kernel_launch(void* const* d_in, const int* in_sizes, int n_in,
                              void* d_out, int out_size, void* d_ws, size_t ws_size,
                              hipStream_t stream) {
    const float* x  = (const float*)d_in[0];   // (B,T,D)
    const float* zf = (const float*)d_in[1];   // (B,P,D)
    float* out = (float*)d_out;                // (B,T+P,D)

    float* ws = (float*)d_ws;
    const size_t NCH = (size_t)B * NC * D;     // 524288
    float* Spart  = ws;                        // reused as carry1
    float* l1e    = Spart + NCH;               // reused as carry2
    float* l2e    = l1e + NCH;
    float* loc    = l2e + NCH;                 // B*D
    float* scf    = loc + (size_t)B * D;       // B*D
    float* carry1 = Spart;                     // alias (see kB)
    float* carry2 = l1e;                       // alias (see kB)

    kA<<<dim3(NC, B), 128, 0, stream>>>(x, Spart, l1e, l2e);
    kB<<<(B * D + 255) / 256, 256, 0, stream>>>(Spart, l1e, l2e, carry1, carry2, loc, scf);
    kC<<<dim3(NC + FB, B), 128, 0, stream>>>(x, carry1, carry2, loc, scf, zf, out);
}